// Round 15
// baseline (137.294 us; speedup 1.0000x reference)
//
#include <hip/hip_runtime.h>
#include <math.h>

// FourierConv2D: B=16,H=W=128,C=16,F=32. FFT 256x256, half-spectrum w in [0,129).
// v14: k3 loads via inline-asm global_load_dwordx4 (un-sinkable) + counted s_waitcnt vmcnt(10)
// + sched_barrier fence -> true depth-1 point pipeline, ~10KB/lane-group in flight.
// Others unchanged from v13 (k1/k2 wave-FFT, k4/k5 512-thr f32-LDS full-line).

constexpr int Bn = 16, Cc = 16, Ff = 32, Hh = 128, Ww = 128, Nn = 256, WH = 129;

#define DEVINL __device__ __forceinline__
DEVINL float2 f2(float a, float b) { return make_float2(a, b); }
DEVINL float2 cmul(float2 a, float2 b) { return f2(a.x * b.x - a.y * b.y, a.x * b.y + a.y * b.x); }

// bf16 pack/unpack (round-half-up)
DEVINL unsigned short f2bf(float f) { unsigned u = __float_as_uint(f); return (unsigned short)((u + 0x8000u) >> 16); }
DEVINL float bf2f(unsigned short h) { return __uint_as_float(((unsigned)h) << 16); }
DEVINL unsigned packbf(float a, float b) { return (unsigned)f2bf(a) | ((unsigned)f2bf(b) << 16); }
DEVINL unsigned pb2(unsigned a, unsigned b) { return packbf(__uint_as_float(a), __uint_as_float(b)); }
DEVINL ushort2 pk2(float2 z) { return make_ushort2(f2bf(z.x), f2bf(z.y)); }
DEVINL float2 up2(ushort2 u) { return f2(bf2f(u.x), bf2f(u.y)); }
DEVINL float2 upu(unsigned u) { return f2(bf2f((unsigned short)(u & 0xffffu)), bf2f((unsigned short)(u >> 16))); }

typedef __attribute__((ext_vector_type(8))) short short8;
typedef __attribute__((ext_vector_type(4))) float f32x4;
typedef __attribute__((ext_vector_type(2))) float fv2;
typedef __attribute__((ext_vector_type(4))) unsigned u32x4;

// un-sinkable 16B global load
#define GLD(dst, addr) asm volatile("global_load_dwordx4 %0, %1, off" : "=v"(dst) : "v"(addr))

// f32 LDS map (float2 elems): row r, elem e; rotation de-aliases the 2KB row stride.
DEVINL int IDX(int r, int e) { return r * 256 + ((e + r) & 255); }

// ---- in-register 16-point FFT ----
template<int SGN>
DEVINL void fft16r(float2 v[16]) {
  float2 t;
#define SW(a,b) { t = v[a]; v[a] = v[b]; v[b] = t; }
  SW(1, 8) SW(2, 4) SW(3, 12) SW(5, 10) SW(7, 14) SW(11, 13)
#undef SW
  const float C1 = 0.92387953251128674f, C2 = 0.70710678118654752f, C3 = 0.38268343236508977f;
  const float Ct[8] = {1.f, C1, C2, C3, 0.f, -C3, -C2, -C1};
  const float St[8] = {0.f, C3, C2, C1, 1.f, C1, C2, C3};
#pragma unroll
  for (int len = 2; len <= 16; len <<= 1) {
    const int half = len >> 1, ts = 16 / len;
#pragma unroll
    for (int i = 0; i < 16; i += len) {
#pragma unroll
      for (int j = 0; j < half; ++j) {
        const float wr = Ct[j * ts];
        const float wi = (SGN > 0) ? St[j * ts] : -St[j * ts];
        float2 b = v[i + j + half];
        float2 tt = f2(wr * b.x - wi * b.y, wr * b.y + wi * b.x);
        float2 a = v[i + j];
        v[i + j]        = f2(a.x + tt.x, a.y + tt.y);
        v[i + j + half] = f2(a.x - tt.x, a.y - tt.y);
      }
    }
  }
}

// twiddle product tree: W[k] = exp(SGN*2pi i*t*k/256), one sincos
template<int SGN>
DEVINL void twiddle16(float2 v[16], int t) {
  const float unit = (SGN > 0) ? 0.024543692606170259f : -0.024543692606170259f;
  float sb, cb;
  __sincosf(unit * (float)t, &sb, &cb);
  float2 W[16];
  W[1] = f2(cb, sb);
#pragma unroll
  for (int k = 2; k < 16; ++k) W[k] = cmul(W[k >> 1], W[k - (k >> 1)]);
#pragma unroll
  for (int k = 1; k < 16; ++k) v[k] = cmul(v[k], W[k]);
}

// ---- f32 256-pt FFT middle, row-local (16-lane slot owns row r) ----
template<int SGN>
DEVINL void fft256_mid(float2 v[16], float2* __restrict__ lds, int r, int t) {
  fft16r<SGN>(v);
  twiddle16<SGN>(v, t);
#pragma unroll
  for (int k = 0; k < 16; ++k) lds[IDX(r, t * 16 + ((k + t) & 15))] = v[k];
#pragma unroll
  for (int n2 = 0; n2 < 16; ++n2) v[n2] = lds[IDX(r, n2 * 16 + ((t + n2) & 15))];
  fft16r<SGN>(v);
}

// ---- K1: per (b,y): 16 row FFTs over x (zero-pad in regs), keep w in [0,129) ----
// R layout: [b][w][y][c]  (bf16 pairs)
__global__ __launch_bounds__(256) void k1_rowfft(const float* __restrict__ img, ushort2* __restrict__ R) {
  __shared__ float2 lds[16 * 256];
  const int tid = threadIdx.x, r = tid >> 4, t = tid & 15;
  const int y = blockIdx.x, b = blockIdx.y;
  const float* ip = img + ((size_t)(b * Hh + y) * Ww) * Cc;
  for (int i = tid; i < Ww * Cc; i += 256) { int x = i >> 4, c = i & 15; lds[IDX(c, x)] = f2(ip[i], 0.f); }
  __syncthreads();
  float2 v[16];
#pragma unroll
  for (int j = 0; j < 8; ++j) v[j] = lds[IDX(r, t + 16 * j)];
#pragma unroll
  for (int j = 8; j < 16; ++j) v[j] = f2(0.f, 0.f);
  fft256_mid<-1>(v, lds, r, t);
#pragma unroll
  for (int k = 0; k < 8; ++k) lds[IDX(r, t + 16 * k)] = v[k];
  if (t == 0) lds[IDX(r, 128)] = v[8];
  __syncthreads();
  ushort2* rp = R + (size_t)b * WH * Hh * Cc + (size_t)y * Cc;
  for (int i = tid; i < WH * Cc; i += 256) {
    int w = i >> 4, c = i & 15;
    rp[(size_t)w * Hh * Cc + c] = pk2(lds[IDX(c, w)]);
  }
}

// ---- K2: per (b,w): 16 column FFTs over y (zero-pad in regs) ----
// Fimg layout: [h][w][b][c]  (bf16 pairs)
__global__ __launch_bounds__(256) void k2_colfft(const ushort2* __restrict__ R, ushort2* __restrict__ Fimg) {
  __shared__ float2 lds[16 * 256];
  const int tid = threadIdx.x, r = tid >> 4, t = tid & 15;
  const int w = blockIdx.x, b = blockIdx.y;
  const ushort2* rp = R + ((size_t)(b * WH + w) * Hh) * Cc;
  for (int i = tid; i < Hh * Cc; i += 256) { int y = i >> 4, c = i & 15; lds[IDX(c, y)] = up2(rp[i]); }
  __syncthreads();
  float2 v[16];
#pragma unroll
  for (int j = 0; j < 8; ++j) v[j] = lds[IDX(r, t + 16 * j)];
#pragma unroll
  for (int j = 8; j < 16; ++j) v[j] = f2(0.f, 0.f);
  fft256_mid<-1>(v, lds, r, t);
#pragma unroll
  for (int k2 = 0; k2 < 16; ++k2) lds[IDX(r, t + 16 * k2)] = v[k2];
  __syncthreads();
  ushort2* fp = Fimg + (size_t)w * 256 + b * 16;
  for (int i = tid; i < Nn * Cc; i += 256) {
    int h = i >> 4, c = i & 15;
    fp[(size_t)h * WH * 256 + c] = pk2(lds[IDX(c, h)]);
  }
}

// ---- K3: per (h,w): out[b,f] = sum_c A[b,c]*(Kr[f,c]+i*Ki[f,c]) via bf16 MFMA ----
// v14: asm global_load_dwordx4 (un-sinkable) + vmcnt(10) counted wait + sched_barrier fence.
// One wave per point, depth-1 point pipeline. OF layout: [w][h][b][f~] interleaved.
constexpr int K3PTS = 4;
__global__ __launch_bounds__(256) void k3_mul(const ushort2* __restrict__ Fimg, const float* __restrict__ Kr,
                                              const float* __restrict__ Ki, ushort2* __restrict__ OF) {
  const int tid = threadIdx.x;
  const int wv = tid >> 6, ln = tid & 63;
  const int w = blockIdx.x, h0 = blockIdx.y * 16 + wv * K3PTS;
  const int q = ln >> 4, fq = ln & 15, m0 = q & 1;
  const bool hi = (q >= 2);
  const int sh = hi ? 16 : 0;
  const unsigned negmask = hi ? 0x80008000u : 0u;

  union U { unsigned u[4]; short8 s; };

  u32x4 a0[2], a1[2];
  u32x4 kA[2], kB[2], kC[2], kD[2];   // Kr tile0(2), tile1(2)
  u32x4 iA[2], iB[2], iC[2], iD[2];   // Ki tile0(2), tile1(2)

  auto aload = [&](int g, int p) {
    const size_t base = (size_t)(h0 + g) * WH + w;
    const char* ap = (const char*)(Fimg + base * 256) + (fq * 4 + 2 * m0) * 16;
    const char* kb = (const char*)(Kr + base * 512 + fq * 16 + 8 * m0);
    const char* ib = (const char*)(Ki + base * 512 + fq * 16 + 8 * m0);
    GLD(a0[p], ap);         GLD(a1[p], ap + 16);
    GLD(kA[p], kb);         GLD(kB[p], kb + 16);
    GLD(kC[p], kb + 1024);  GLD(kD[p], kb + 1040);
    GLD(iA[p], ib);         GLD(iB[p], ib + 16);
    GLD(iC[p], ib + 1024);  GLD(iD[p], ib + 1040);
  };

  auto compute = [&](int g, int p) {
    U ua;
    ua.u[0] = ((a0[p].x >> sh) & 0xffffu) | (((a0[p].y >> sh) & 0xffffu) << 16);
    ua.u[1] = ((a0[p].z >> sh) & 0xffffu) | (((a0[p].w >> sh) & 0xffffu) << 16);
    ua.u[2] = ((a1[p].x >> sh) & 0xffffu) | (((a1[p].y >> sh) & 0xffffu) << 16);
    ua.u[3] = ((a1[p].z >> sh) & 0xffffu) | (((a1[p].w >> sh) & 0xffffu) << 16);

    U ubr0, ubi0, ubr1, ubi1;
    {
      unsigned krP[4] = { pb2(kA[p].x, kA[p].y), pb2(kA[p].z, kA[p].w),
                          pb2(kB[p].x, kB[p].y), pb2(kB[p].z, kB[p].w) };
      unsigned kiP[4] = { pb2(iA[p].x, iA[p].y), pb2(iA[p].z, iA[p].w),
                          pb2(iB[p].x, iB[p].y), pb2(iB[p].z, iB[p].w) };
#pragma unroll
      for (int j = 0; j < 4; ++j) {
        ubr0.u[j] = (hi ? kiP[j] : krP[j]) ^ negmask;   // [Kr | -Ki]
        ubi0.u[j] = hi ? krP[j] : kiP[j];               // [Ki |  Kr]
      }
    }
    {
      unsigned krP[4] = { pb2(kC[p].x, kC[p].y), pb2(kC[p].z, kC[p].w),
                          pb2(kD[p].x, kD[p].y), pb2(kD[p].z, kD[p].w) };
      unsigned kiP[4] = { pb2(iC[p].x, iC[p].y), pb2(iC[p].z, iC[p].w),
                          pb2(iD[p].x, iD[p].y), pb2(iD[p].z, iD[p].w) };
#pragma unroll
      for (int j = 0; j < 4; ++j) {
        ubr1.u[j] = (hi ? kiP[j] : krP[j]) ^ negmask;
        ubi1.u[j] = hi ? krP[j] : kiP[j];
      }
    }

    f32x4 aR0 = {0.f, 0.f, 0.f, 0.f}, aI0 = {0.f, 0.f, 0.f, 0.f};
    f32x4 aR1 = {0.f, 0.f, 0.f, 0.f}, aI1 = {0.f, 0.f, 0.f, 0.f};
    aR0 = __builtin_amdgcn_mfma_f32_16x16x32_bf16(ua.s, ubr0.s, aR0, 0, 0, 0);
    aI0 = __builtin_amdgcn_mfma_f32_16x16x32_bf16(ua.s, ubi0.s, aI0, 0, 0, 0);
    aR1 = __builtin_amdgcn_mfma_f32_16x16x32_bf16(ua.s, ubr1.s, aR1, 0, 0, 0);
    aI1 = __builtin_amdgcn_mfma_f32_16x16x32_bf16(ua.s, ubi1.s, aI1, 0, 0, 0);

    uint2* op = (uint2*)(OF + ((size_t)w * 256 + (h0 + g)) * 512);   // 256 uint2 per point
#pragma unroll
    for (int reg = 0; reg < 4; ++reg)
      op[(4 * q + reg) * 16 + fq] = make_uint2(packbf(aR0[reg], aI0[reg]),
                                               packbf(aR1[reg], aI1[reg]));
  };

  aload(0, 0);
#pragma unroll
  for (int g = 0; g < K3PTS; ++g) {
    if (g + 1 < K3PTS) {
      aload(g + 1, (g + 1) & 1);               // 10 more loads in flight
      asm volatile("s_waitcnt vmcnt(10)");     // wait point g's loads (all but 10 newest)
    } else {
      asm volatile("s_waitcnt vmcnt(0)");
    }
    __builtin_amdgcn_sched_barrier(0);         // rule #18: nothing hoists above the wait
    compute(g, g & 1);
  }
}

// ---- K4: per (w,b): 32 inverse column FFTs over h; store y' = h-63 in [0,128) ----
// 512 threads: slot s = tid>>4 owns f-row s. f32 LDS 64KB. 8B/lane global ops.
// OF is f-interleaved: dword pair (2fh,2fh+1) = f (fh, fh+16). T layout: [b][y'][w][f] canonical.
__global__ __launch_bounds__(512) void k4_colifft(const ushort2* __restrict__ OF, ushort2* __restrict__ T) {
  __shared__ float2 lds[32 * 256];   // 64 KB
  const int tid = threadIdx.x, s = tid >> 4, t = tid & 15;
  const int bidx = blockIdx.x;
  const int b = bidx & 15, w = bidx >> 4;
  const int fh = tid & 15;
  const uint2* ofp2 = (const uint2*)OF + (size_t)w * 65536;   // + h*256 + b*16 + fh (uint2 units)
  for (int i = tid; i < Nn * 16; i += 512) {
    int h = i >> 4;
    uint2 u = ofp2[(size_t)h * 256 + b * 16 + fh];
    lds[IDX(fh, h)]      = upu(u.x);   // f = fh
    lds[IDX(fh + 16, h)] = upu(u.y);   // f = fh+16
  }
  __syncthreads();
  float2 v[16];
#pragma unroll
  for (int j = 0; j < 16; ++j) v[j] = lds[IDX(s, t + 16 * j)];
  fft256_mid<1>(v, lds, s, t);
#pragma unroll
  for (int k2 = 3; k2 < 12; ++k2) lds[IDX(s, t + 16 * k2)] = v[k2];  // elems 48..191 cover 63..190
  __syncthreads();
  ushort4* tp4 = (ushort4*)T + ((size_t)b * Hh * WH) * 16 + (size_t)w * 16;
  for (int i = tid; i < Hh * 16; i += 512) {
    int yp = i >> 4;
    float2 z0 = lds[IDX(2 * fh, 63 + yp)];
    float2 z1 = lds[IDX(2 * fh + 1, 63 + yp)];
    ushort4 st; st.x = f2bf(z0.x); st.y = f2bf(z0.y); st.z = f2bf(z1.x); st.w = f2bf(z1.y);
    tp4[(size_t)yp * WH * 16 + fh] = st;
  }
}

// ---- K5: per (b,y'): Hermitian-extend w-spectrum, 32 inverse FFTs, Re, scale, +bias, crop x ----
// 512 threads, f32 LDS 64KB, 8B/lane global ops. out f32 (nontemporal stores).
__global__ __launch_bounds__(512) void k5_rowifft(const ushort2* __restrict__ T, const float* __restrict__ bias,
                                                  float* __restrict__ out) {
  __shared__ float2 lds[32 * 256];   // 64 KB
  const int tid = threadIdx.x, s = tid >> 4, t = tid & 15;
  const int yp = blockIdx.x, b = blockIdx.y;
  const int fh = tid & 15;
  const ushort4* tp4 = (const ushort4*)T + ((size_t)(b * Hh + yp) * WH) * 16;  // + w*16 + fh
  for (int i = tid; i < WH * 16; i += 512) {
    int w = i >> 4;
    ushort4 u = tp4[(size_t)w * 16 + fh];
    lds[IDX(2 * fh, w)]     = f2(bf2f(u.x), bf2f(u.y));
    lds[IDX(2 * fh + 1, w)] = f2(bf2f(u.z), bf2f(u.w));
  }
  __syncthreads();
  float2 v[16];
#pragma unroll
  for (int n1 = 0; n1 < 16; ++n1) {                 // Hermitian mirror folded into reg load
    const int c = t + 16 * n1;
    if (c <= 128) v[n1] = lds[IDX(s, c)];
    else { float2 z = lds[IDX(s, 256 - c)]; v[n1] = f2(z.x, -z.y); }
  }
  fft256_mid<1>(v, lds, s, t);
#pragma unroll
  for (int k2 = 3; k2 < 12; ++k2) lds[IDX(s, t + 16 * k2)] = v[k2];
  __syncthreads();
  const float sc = 1.f / 65536.f;
  const float bv0 = bias[2 * fh], bv1 = bias[2 * fh + 1];
  fv2* op = (fv2*)(out + ((size_t)(b * Hh + yp) * Ww) * Ff);   // + x*16 + fh (fv2 units)
  for (int i = tid; i < Ww * 16; i += 512) {
    int x = i >> 4;
    fv2 st;
    st.x = lds[IDX(2 * fh, 63 + x)].x * sc + bv0;
    st.y = lds[IDX(2 * fh + 1, 63 + x)].x * sc + bv1;
    __builtin_nontemporal_store(st, &op[(size_t)x * 16 + fh]);
  }
}

extern "C" void kernel_launch(void* const* d_in, const int* in_sizes, int n_in,
                              void* d_out, int out_size, void* d_ws, size_t ws_size,
                              hipStream_t stream) {
  const float* img  = (const float*)d_in[0];
  const float* kr   = (const float*)d_in[1];
  const float* ki   = (const float*)d_in[2];
  const float* bias = (const float*)d_in[3];
  float* out = (float*)d_out;

  char* ws = (char*)d_ws;
  // region layout (lifetime-overlapped):
  //   [0, 67.6MB):     Fimg bf16 (K2->K3, 33.8MB), later T bf16 (K4->K5, 33.8MB)
  //   [67.6MB, 135MB): OF bf16 (K3->K4, 67.6MB); R bf16 (K1->K2, 16.9MB) aliases its head
  const size_t szF = (size_t)Nn * WH * Bn * Cc * sizeof(float2);   // 67,633,152
  ushort2* Fimg = (ushort2*)ws;
  ushort2* T    = (ushort2*)ws;
  ushort2* OF   = (ushort2*)(ws + szF);
  ushort2* R    = (ushort2*)(ws + szF);

  k1_rowfft <<<dim3(Hh, Bn),   256, 0, stream>>>(img, R);
  k2_colfft <<<dim3(WH, Bn),   256, 0, stream>>>(R, Fimg);
  k3_mul    <<<dim3(WH, 16),   256, 0, stream>>>(Fimg, kr, ki, OF);
  k4_colifft<<<dim3(WH * Bn),  512, 0, stream>>>(OF, T);
  k5_rowifft<<<dim3(Hh, Bn),   512, 0, stream>>>(T, bias, out);
}

// Round 16
// 133.866 us; speedup vs baseline: 1.0256x; 1.0256x over previous
//
#include <hip/hip_runtime.h>
#include <math.h>

// FourierConv2D: B=16,H=W=128,C=16,F=32. FFT 256x256, half-spectrum w in [0,129).
// v15: k1/k2 -> 512-thread blocks covering 2 y's / 2 b's so ALL global stores are full
// 128B lines (kills write-allocate on R and Fimg); k4/k5 staging widened to 16B/lane.
// k3 = v13 (2-wave MFMA, best measured). Layouts unchanged.

constexpr int Bn = 16, Cc = 16, Ff = 32, Hh = 128, Ww = 128, Nn = 256, WH = 129;

#define DEVINL __device__ __forceinline__
DEVINL float2 f2(float a, float b) { return make_float2(a, b); }
DEVINL float2 cmul(float2 a, float2 b) { return f2(a.x * b.x - a.y * b.y, a.x * b.y + a.y * b.x); }

DEVINL unsigned short f2bf(float f) { unsigned u = __float_as_uint(f); return (unsigned short)((u + 0x8000u) >> 16); }
DEVINL float bf2f(unsigned short h) { return __uint_as_float(((unsigned)h) << 16); }
DEVINL unsigned packbf(float a, float b) { return (unsigned)f2bf(a) | ((unsigned)f2bf(b) << 16); }
DEVINL unsigned pk2u(float2 z) { return packbf(z.x, z.y); }
DEVINL ushort2 pk2(float2 z) { return make_ushort2(f2bf(z.x), f2bf(z.y)); }
DEVINL float2 up2(ushort2 u) { return f2(bf2f(u.x), bf2f(u.y)); }
DEVINL float2 upu(unsigned u) { return f2(bf2f((unsigned short)(u & 0xffffu)), bf2f((unsigned short)(u >> 16))); }

typedef __attribute__((ext_vector_type(8))) short short8;
typedef __attribute__((ext_vector_type(4))) float f32x4;
typedef __attribute__((ext_vector_type(4))) float fv4;

// f32 LDS map (float2 elems): row r, elem e; rotation de-aliases the 2KB row stride.
DEVINL int IDX(int r, int e) { return r * 256 + ((e + r) & 255); }

// ---- in-register 16-point FFT ----
template<int SGN>
DEVINL void fft16r(float2 v[16]) {
  float2 t;
#define SW(a,b) { t = v[a]; v[a] = v[b]; v[b] = t; }
  SW(1, 8) SW(2, 4) SW(3, 12) SW(5, 10) SW(7, 14) SW(11, 13)
#undef SW
  const float C1 = 0.92387953251128674f, C2 = 0.70710678118654752f, C3 = 0.38268343236508977f;
  const float Ct[8] = {1.f, C1, C2, C3, 0.f, -C3, -C2, -C1};
  const float St[8] = {0.f, C3, C2, C1, 1.f, C1, C2, C3};
#pragma unroll
  for (int len = 2; len <= 16; len <<= 1) {
    const int half = len >> 1, ts = 16 / len;
#pragma unroll
    for (int i = 0; i < 16; i += len) {
#pragma unroll
      for (int j = 0; j < half; ++j) {
        const float wr = Ct[j * ts];
        const float wi = (SGN > 0) ? St[j * ts] : -St[j * ts];
        float2 b = v[i + j + half];
        float2 tt = f2(wr * b.x - wi * b.y, wr * b.y + wi * b.x);
        float2 a = v[i + j];
        v[i + j]        = f2(a.x + tt.x, a.y + tt.y);
        v[i + j + half] = f2(a.x - tt.x, a.y - tt.y);
      }
    }
  }
}

template<int SGN>
DEVINL void twiddle16(float2 v[16], int t) {
  const float unit = (SGN > 0) ? 0.024543692606170259f : -0.024543692606170259f;
  float sb, cb;
  __sincosf(unit * (float)t, &sb, &cb);
  float2 W[16];
  W[1] = f2(cb, sb);
#pragma unroll
  for (int k = 2; k < 16; ++k) W[k] = cmul(W[k >> 1], W[k - (k >> 1)]);
#pragma unroll
  for (int k = 1; k < 16; ++k) v[k] = cmul(v[k], W[k]);
}

// ---- f32 256-pt FFT middle, row-local (16-lane slot owns row r) ----
template<int SGN>
DEVINL void fft256_mid(float2 v[16], float2* __restrict__ lds, int r, int t) {
  fft16r<SGN>(v);
  twiddle16<SGN>(v, t);
#pragma unroll
  for (int k = 0; k < 16; ++k) lds[IDX(r, t * 16 + ((k + t) & 15))] = v[k];
#pragma unroll
  for (int n2 = 0; n2 < 16; ++n2) v[n2] = lds[IDX(r, n2 * 16 + ((t + n2) & 15))];
  fft16r<SGN>(v);
}

// ---- K1: per (b, y-pair): 32 row FFTs over x (rows = yb*16+c). 512 threads.
// R layout: [b][w][y][c] (bf16 pairs); per w a block writes 2y*16c = 128B full line.
__global__ __launch_bounds__(512) void k1_rowfft(const float* __restrict__ img, ushort2* __restrict__ R) {
  __shared__ float2 lds[32 * 256];   // 64 KB
  const int tid = threadIdx.x, s = tid >> 4, t = tid & 15;
  const int y0 = blockIdx.x * 2, b = blockIdx.y;
  const float4* ip4 = (const float4*)(img + ((size_t)(b * Hh + y0) * Ww) * Cc);
  for (int i = tid; i < 2 * Ww * 4; i += 512) {      // 1024 float4
    int yb = i >> 9, rem = i & 511, x = rem >> 2, j = rem & 3;
    float4 u = ip4[(size_t)yb * 512 + rem];
    lds[IDX(yb * 16 + 4 * j + 0, x)] = f2(u.x, 0.f);
    lds[IDX(yb * 16 + 4 * j + 1, x)] = f2(u.y, 0.f);
    lds[IDX(yb * 16 + 4 * j + 2, x)] = f2(u.z, 0.f);
    lds[IDX(yb * 16 + 4 * j + 3, x)] = f2(u.w, 0.f);
  }
  __syncthreads();
  float2 v[16];
#pragma unroll
  for (int j = 0; j < 8; ++j) v[j] = lds[IDX(s, t + 16 * j)];
#pragma unroll
  for (int j = 8; j < 16; ++j) v[j] = f2(0.f, 0.f);
  fft256_mid<-1>(v, lds, s, t);
#pragma unroll
  for (int k = 0; k < 8; ++k) lds[IDX(s, t + 16 * k)] = v[k];
  if (t == 0) lds[IDX(s, 128)] = v[8];
  __syncthreads();
  ushort2* rp = R + ((size_t)b * WH * Hh + y0) * Cc;
  for (int i = tid; i < WH * 32; i += 512) {
    int w = i >> 5, row = i & 31;                    // row = yb*16+c
    rp[(size_t)w * Hh * Cc + row] = pk2(lds[IDX(row, w)]);
  }
}

// ---- K2: per (w, b-pair): 32 column FFTs over y (rows = bb*16+c). 512 threads.
// Fimg layout: [h][w][b][c]; per h a block writes 2b*16c = 128B full line.
__global__ __launch_bounds__(512) void k2_colfft(const ushort2* __restrict__ R, ushort2* __restrict__ Fimg) {
  __shared__ float2 lds[32 * 256];   // 64 KB
  const int tid = threadIdx.x, s = tid >> 4, t = tid & 15;
  const int w = blockIdx.x, b0 = blockIdx.y * 2;
  const uint4* rp4 = (const uint4*)(R + ((size_t)(b0 * WH + w) * Hh) * Cc);
  const size_t bstride4 = (size_t)WH * Hh * Cc / 4;  // uint4 units per b
  for (int i = tid; i < 2 * Hh * 4; i += 512) {      // 1024 uint4
    int bb = i >> 9, rem = i & 511, y = rem >> 2, j = rem & 3;
    uint4 u = rp4[(size_t)bb * bstride4 + rem];
    lds[IDX(bb * 16 + 4 * j + 0, y)] = upu(u.x);
    lds[IDX(bb * 16 + 4 * j + 1, y)] = upu(u.y);
    lds[IDX(bb * 16 + 4 * j + 2, y)] = upu(u.z);
    lds[IDX(bb * 16 + 4 * j + 3, y)] = upu(u.w);
  }
  __syncthreads();
  float2 v[16];
#pragma unroll
  for (int j = 0; j < 8; ++j) v[j] = lds[IDX(s, t + 16 * j)];
#pragma unroll
  for (int j = 8; j < 16; ++j) v[j] = f2(0.f, 0.f);
  fft256_mid<-1>(v, lds, s, t);
#pragma unroll
  for (int k2 = 0; k2 < 16; ++k2) lds[IDX(s, t + 16 * k2)] = v[k2];
  __syncthreads();
  ushort2* fp = Fimg + (size_t)w * 256 + b0 * 16;
  for (int i = tid; i < Nn * 32; i += 512) {
    int h = i >> 5, row = i & 31;                    // row = bb*16+c
    fp[(size_t)h * WH * 256 + row] = pk2(lds[IDX(row, h)]);
  }
}

// ---- K3: per (h,w): out[b,f] = sum_c A[b,c]*(Kr[f,c]+i*Ki[f,c]) via bf16 MFMA (v13) ----
// 2-wave blocks; each wave loads TWO points fully up front, sched_barrier, computes both.
// OF layout: [w][h][b][f~] interleaved (full 128B-line stores).
constexpr int K3PTS = 2;
__global__ __launch_bounds__(128) void k3_mul(const ushort2* __restrict__ Fimg, const float* __restrict__ Kr,
                                              const float* __restrict__ Ki, ushort2* __restrict__ OF) {
  const int tid = threadIdx.x;
  const int wv = tid >> 6, ln = tid & 63;
  const int w = blockIdx.x, h0 = blockIdx.y * (2 * K3PTS) + wv * K3PTS;
  const int q = ln >> 4, fq = ln & 15, m0 = q & 1;
  const bool hi = (q >= 2);
  const int sh = hi ? 16 : 0;
  const unsigned negmask = hi ? 0x80008000u : 0u;

  union U { unsigned u[4]; short8 s; };

  uint4  a0[2], a1[2];
  float4 kA[2], kB[2], kC[2], kD[2];
  float4 iA[2], iB[2], iC[2], iD[2];

  auto load = [&](int g, int p) {
    const size_t base = (size_t)(h0 + g) * WH + w;
    const uint4* ap = (const uint4*)(Fimg + base * 256);
    a0[p] = ap[fq * 4 + 2 * m0];
    a1[p] = ap[fq * 4 + 2 * m0 + 1];
    const float* kb = Kr + base * 512 + fq * 16 + 8 * m0;
    const float* ib = Ki + base * 512 + fq * 16 + 8 * m0;
    kA[p] = *(const float4*)kb;          kB[p] = *(const float4*)(kb + 4);
    kC[p] = *(const float4*)(kb + 256);  kD[p] = *(const float4*)(kb + 260);
    iA[p] = *(const float4*)ib;          iB[p] = *(const float4*)(ib + 4);
    iC[p] = *(const float4*)(ib + 256);  iD[p] = *(const float4*)(ib + 260);
  };

  auto compute = [&](int g, int p) {
    U ua;
    ua.u[0] = ((a0[p].x >> sh) & 0xffffu) | (((a0[p].y >> sh) & 0xffffu) << 16);
    ua.u[1] = ((a0[p].z >> sh) & 0xffffu) | (((a0[p].w >> sh) & 0xffffu) << 16);
    ua.u[2] = ((a1[p].x >> sh) & 0xffffu) | (((a1[p].y >> sh) & 0xffffu) << 16);
    ua.u[3] = ((a1[p].z >> sh) & 0xffffu) | (((a1[p].w >> sh) & 0xffffu) << 16);

    U ubr0, ubi0, ubr1, ubi1;
    {
      unsigned krP[4] = { packbf(kA[p].x, kA[p].y), packbf(kA[p].z, kA[p].w),
                          packbf(kB[p].x, kB[p].y), packbf(kB[p].z, kB[p].w) };
      unsigned kiP[4] = { packbf(iA[p].x, iA[p].y), packbf(iA[p].z, iA[p].w),
                          packbf(iB[p].x, iB[p].y), packbf(iB[p].z, iB[p].w) };
#pragma unroll
      for (int j = 0; j < 4; ++j) {
        ubr0.u[j] = (hi ? kiP[j] : krP[j]) ^ negmask;   // [Kr | -Ki]
        ubi0.u[j] = hi ? krP[j] : kiP[j];               // [Ki |  Kr]
      }
    }
    {
      unsigned krP[4] = { packbf(kC[p].x, kC[p].y), packbf(kC[p].z, kC[p].w),
                          packbf(kD[p].x, kD[p].y), packbf(kD[p].z, kD[p].w) };
      unsigned kiP[4] = { packbf(iC[p].x, iC[p].y), packbf(iC[p].z, iC[p].w),
                          packbf(iD[p].x, iD[p].y), packbf(iD[p].z, iD[p].w) };
#pragma unroll
      for (int j = 0; j < 4; ++j) {
        ubr1.u[j] = (hi ? kiP[j] : krP[j]) ^ negmask;
        ubi1.u[j] = hi ? krP[j] : kiP[j];
      }
    }

    f32x4 aR0 = {0.f, 0.f, 0.f, 0.f}, aI0 = {0.f, 0.f, 0.f, 0.f};
    f32x4 aR1 = {0.f, 0.f, 0.f, 0.f}, aI1 = {0.f, 0.f, 0.f, 0.f};
    aR0 = __builtin_amdgcn_mfma_f32_16x16x32_bf16(ua.s, ubr0.s, aR0, 0, 0, 0);
    aI0 = __builtin_amdgcn_mfma_f32_16x16x32_bf16(ua.s, ubi0.s, aI0, 0, 0, 0);
    aR1 = __builtin_amdgcn_mfma_f32_16x16x32_bf16(ua.s, ubr1.s, aR1, 0, 0, 0);
    aI1 = __builtin_amdgcn_mfma_f32_16x16x32_bf16(ua.s, ubi1.s, aI1, 0, 0, 0);

    uint2* op = (uint2*)(OF + ((size_t)w * 256 + (h0 + g)) * 512);
#pragma unroll
    for (int reg = 0; reg < 4; ++reg)
      op[(4 * q + reg) * 16 + fq] = make_uint2(packbf(aR0[reg], aI0[reg]),
                                               packbf(aR1[reg], aI1[reg]));
  };

  load(0, 0);
  load(1, 1);
  __builtin_amdgcn_sched_barrier(0);
  compute(0, 0);
  compute(1, 1);
}

// ---- K4: per (w,b): 32 inverse column FFTs over h; store y' = h-63 in [0,128) ----
// 512 threads, f32 LDS 64KB, 16B/lane global ops. T layout: [b][y'][w][f] canonical.
__global__ __launch_bounds__(512) void k4_colifft(const ushort2* __restrict__ OF, ushort2* __restrict__ T) {
  __shared__ float2 lds[32 * 256];   // 64 KB
  const int tid = threadIdx.x, s = tid >> 4, t = tid & 15;
  const int bidx = blockIdx.x;
  const int b = bidx & 15, w = bidx >> 4;
  const int j8 = tid & 7;
  const uint4* ofp4 = (const uint4*)OF + (size_t)w * 32768;   // + h*128 + b*8 + j (uint4 units)
  for (int i = tid; i < Nn * 8; i += 512) {
    int h = i >> 3, j = i & 7;
    uint4 u = ofp4[(size_t)h * 128 + b * 8 + j];
    lds[IDX(2 * j, h)]      = upu(u.x);   // f = 2j
    lds[IDX(2 * j + 16, h)] = upu(u.y);   // f = 2j+16
    lds[IDX(2 * j + 1, h)]  = upu(u.z);   // f = 2j+1
    lds[IDX(2 * j + 17, h)] = upu(u.w);   // f = 2j+17
  }
  __syncthreads();
  float2 v[16];
#pragma unroll
  for (int j = 0; j < 16; ++j) v[j] = lds[IDX(s, t + 16 * j)];
  fft256_mid<1>(v, lds, s, t);
#pragma unroll
  for (int k2 = 3; k2 < 12; ++k2) lds[IDX(s, t + 16 * k2)] = v[k2];  // elems 48..191 cover 63..190
  __syncthreads();
  uint4* tp4 = (uint4*)T + ((size_t)b * Hh * WH + w) * 8;
  for (int i = tid; i < Hh * 8; i += 512) {
    int yp = i >> 3, j = i & 7;
    uint4 st;
    st.x = pk2u(lds[IDX(4 * j + 0, 63 + yp)]);
    st.y = pk2u(lds[IDX(4 * j + 1, 63 + yp)]);
    st.z = pk2u(lds[IDX(4 * j + 2, 63 + yp)]);
    st.w = pk2u(lds[IDX(4 * j + 3, 63 + yp)]);
    tp4[(size_t)yp * WH * 8 + j] = st;
  }
  (void)j8;
}

// ---- K5: per (b,y'): Hermitian-extend w-spectrum, 32 inverse FFTs, Re, scale, +bias, crop x ----
// 512 threads, f32 LDS 64KB, 16B/lane global ops. out f32 (nontemporal fv4 stores).
__global__ __launch_bounds__(512) void k5_rowifft(const ushort2* __restrict__ T, const float* __restrict__ bias,
                                                  float* __restrict__ out) {
  __shared__ float2 lds[32 * 256];   // 64 KB
  const int tid = threadIdx.x, s = tid >> 4, t = tid & 15;
  const int yp = blockIdx.x, b = blockIdx.y;
  const uint4* tp4 = (const uint4*)T + ((size_t)(b * Hh + yp) * WH) * 8;  // + w*8 + j
  for (int i = tid; i < WH * 8; i += 512) {
    int w = i >> 3, j = i & 7;
    uint4 u = tp4[(size_t)w * 8 + j];
    lds[IDX(4 * j + 0, w)] = upu(u.x);
    lds[IDX(4 * j + 1, w)] = upu(u.y);
    lds[IDX(4 * j + 2, w)] = upu(u.z);
    lds[IDX(4 * j + 3, w)] = upu(u.w);
  }
  __syncthreads();
  float2 v[16];
#pragma unroll
  for (int n1 = 0; n1 < 16; ++n1) {                 // Hermitian mirror folded into reg load
    const int c = t + 16 * n1;
    if (c <= 128) v[n1] = lds[IDX(s, c)];
    else { float2 z = lds[IDX(s, 256 - c)]; v[n1] = f2(z.x, -z.y); }
  }
  fft256_mid<1>(v, lds, s, t);
#pragma unroll
  for (int k2 = 3; k2 < 12; ++k2) lds[IDX(s, t + 16 * k2)] = v[k2];
  __syncthreads();
  const float sc = 1.f / 65536.f;
  const int j8 = tid & 7;
  const float bv0 = bias[4 * j8 + 0], bv1 = bias[4 * j8 + 1];
  const float bv2 = bias[4 * j8 + 2], bv3 = bias[4 * j8 + 3];
  fv4* op = (fv4*)(out + ((size_t)(b * Hh + yp) * Ww) * Ff);   // + x*8 + j (fv4 units)
  for (int i = tid; i < Ww * 8; i += 512) {
    int x = i >> 3, j = i & 7;
    fv4 st;
    st.x = lds[IDX(4 * j + 0, 63 + x)].x * sc + bv0;
    st.y = lds[IDX(4 * j + 1, 63 + x)].x * sc + bv1;
    st.z = lds[IDX(4 * j + 2, 63 + x)].x * sc + bv2;
    st.w = lds[IDX(4 * j + 3, 63 + x)].x * sc + bv3;
    __builtin_nontemporal_store(st, &op[(size_t)x * 8 + j]);
  }
}

extern "C" void kernel_launch(void* const* d_in, const int* in_sizes, int n_in,
                              void* d_out, int out_size, void* d_ws, size_t ws_size,
                              hipStream_t stream) {
  const float* img  = (const float*)d_in[0];
  const float* kr   = (const float*)d_in[1];
  const float* ki   = (const float*)d_in[2];
  const float* bias = (const float*)d_in[3];
  float* out = (float*)d_out;

  char* ws = (char*)d_ws;
  // region layout (lifetime-overlapped):
  //   [0, 67.6MB):     Fimg bf16 (K2->K3, 33.8MB), later T bf16 (K4->K5, 33.8MB)
  //   [67.6MB, 135MB): OF bf16 (K3->K4, 67.6MB); R bf16 (K1->K2, 16.9MB) aliases its head
  const size_t szF = (size_t)Nn * WH * Bn * Cc * sizeof(float2);   // 67,633,152
  ushort2* Fimg = (ushort2*)ws;
  ushort2* T    = (ushort2*)ws;
  ushort2* OF   = (ushort2*)(ws + szF);
  ushort2* R    = (ushort2*)(ws + szF);

  k1_rowfft <<<dim3(Hh / 2, Bn),  512, 0, stream>>>(img, R);
  k2_colfft <<<dim3(WH, Bn / 2),  512, 0, stream>>>(R, Fimg);
  k3_mul    <<<dim3(WH, 64),      128, 0, stream>>>(Fimg, kr, ki, OF);
  k4_colifft<<<dim3(WH * Bn),     512, 0, stream>>>(OF, T);
  k5_rowifft<<<dim3(Hh, Bn),      512, 0, stream>>>(T, bias, out);
}